// Round 5
// baseline (127.900 us; speedup 1.0000x reference)
//
#include <hip/hip_runtime.h>
#include <math.h>

#define C 10
#define BLOCK 256
#define NBLOCKS 1024
#define WROWS 128                    // rows per wave-tile (2 rows per lane)
#define NSTATS (3 * C)               // 30 series

// 4B-aligned vector types: row base addresses are 40B multiples, so only
// dword alignment is guaranteed. gfx9+ global_load_dwordx4 needs only 4B.
typedef float f4 __attribute__((ext_vector_type(4), aligned(4)));
typedef float f2 __attribute__((ext_vector_type(2), aligned(4)));

// ---------------- row accumulate (softmax sufficient statistics) ----------------

__device__ __forceinline__ void accum10(f4 r0, f4 r1, f2 r2,
                                        float* __restrict__ s1,
                                        float* __restrict__ s2,
                                        float* __restrict__ sl) {
  float v[C];
  v[0] = r0.x; v[1] = r0.y; v[2] = r0.z; v[3] = r0.w;
  v[4] = r1.x; v[5] = r1.y; v[6] = r1.z; v[7] = r1.w;
  v[8] = r2.x; v[9] = r2.y;
  float mx = v[0];
#pragma unroll
  for (int c = 1; c < C; c++) mx = fmaxf(mx, v[c]);
  float e[C], se = 0.f;
#pragma unroll
  for (int c = 0; c < C; c++) { v[c] -= mx; e[c] = __expf(v[c]); se += e[c]; }
  float inv = 1.0f / se;
  float lse = __logf(se);
#pragma unroll
  for (int c = 0; c < C; c++) {
    float p = e[c] * inv;
    s1[c] += p;
    s2[c] = fmaf(p, p, s2[c]);
    sl[c] += v[c] - lse;             // log p = (x - mx) - lse
  }
}

// ---------------- Kernel 1: LDS-free stats — MEASUREMENT ROUND: 2 passes --------
// ATTRIBUTION EXPERIMENT: the whole grid-stride loop runs TWICE, so every stat
// sum is exactly doubled (sum+sum = exact *2). Kernel 2 receives nd = 2n, and
// the Newton trajectory is bit-identical ((2S)/(2n) == S/n in IEEE; all n-scaled
// quantities cancel exactly). Delta(total) vs last round measures the stats
// kernel's marginal cost directly; if ~>49us it also enters the rocprof top-5
// and we finally get its VALUBusy/Occupancy/FETCH.

__global__ __launch_bounds__(BLOCK) void dir_stats_kernel(
    const float* __restrict__ x, float* __restrict__ partials,
    int nrows, int nblocks) {
  __shared__ float red[4][NSTATS];
  const int tid = threadIdx.x;
  const int lane = tid & 63;
  const int wave = tid >> 6;

  const int gwave = blockIdx.x * 4 + wave;   // global wave id
  const int wstride = nblocks * 4;
  const int ntiles = nrows / WROWS;
  const int tailStart = ntiles * WROWS;

  float s1[C], s2[C], sl[C];
#pragma unroll
  for (int c = 0; c < C; c++) { s1[c] = 0.f; s2[c] = 0.f; sl[c] = 0.f; }

  for (int pass = 0; pass < 2; pass++) {
    int g = gwave;
    f4 a0 = 0, a1 = 0, b0 = 0, b1 = 0, n0 = 0, n1 = 0, m0 = 0, m1 = 0;
    f2 a2 = 0, b2 = 0, n2 = 0, m2 = 0;
    if (g < ntiles) {                        // prologue: rows (g*128+lane), (+64)
      const float* p = x + ((size_t)g * WROWS + lane) * C;
      a0 = *(const f4*)(p);       a1 = *(const f4*)(p + 4);   a2 = *(const f2*)(p + 8);
      b0 = *(const f4*)(p + 640); b1 = *(const f4*)(p + 644); b2 = *(const f2*)(p + 648);
    }
    while (g < ntiles) {
      const int gn = g + wstride;            // issue next tile's loads NOW
      if (gn < ntiles) {
        const float* p = x + ((size_t)gn * WROWS + lane) * C;
        n0 = *(const f4*)(p);       n1 = *(const f4*)(p + 4);   n2 = *(const f2*)(p + 8);
        m0 = *(const f4*)(p + 640); m1 = *(const f4*)(p + 644); m2 = *(const f2*)(p + 648);
      }
      accum10(a0, a1, a2, s1, s2, sl);       // compute on current regs (no dep on loads)
      accum10(b0, b1, b2, s1, s2, sl);
      a0 = n0; a1 = n1; a2 = n2;             // vmcnt wait lands here, after compute
      b0 = m0; b1 = m1; b2 = m2;
      g = gn;
    }

    if (gwave == wstride - 1) {              // tail rows (none when nrows%128==0)
      for (int rr = tailStart + lane; rr < nrows; rr += 64) {
        const float* r = x + (size_t)rr * C;
        f4 t0 = *(const f4*)(r);
        f4 t1 = *(const f4*)(r + 4);
        f2 t2 = *(const f2*)(r + 8);
        accum10(t0, t1, t2, s1, s2, sl);
      }
    }
  }

  // block reduction: wave shuffle, then cross-wave via LDS (single barrier)
#pragma unroll
  for (int c = 0; c < C; c++) {
    float v1 = s1[c], v2 = s2[c], v3 = sl[c];
#pragma unroll
    for (int off = 32; off >= 1; off >>= 1) {
      v1 += __shfl_down(v1, off);
      v2 += __shfl_down(v2, off);
      v3 += __shfl_down(v3, off);
    }
    if (lane == 0) {
      red[wave][c] = v1;
      red[wave][C + c] = v2;
      red[wave][2 * C + c] = v3;
    }
  }
  __syncthreads();
  if (tid < NSTATS) {
    float tot = red[0][tid] + red[1][tid] + red[2][tid] + red[3][tid];
    partials[(size_t)tid * nblocks + blockIdx.x] = tot;   // SoA over blocks
  }
}

// ---------------- fast fp64 reciprocal: v_rcp_f64 + 2 NR steps (<=1 ulp) --------

__device__ __forceinline__ double frcp(double x) {
  double r;
  asm("v_rcp_f64 %0, %1" : "=v"(r) : "v"(x));
  double e = fma(-x, r, 1.0);
  r = fma(r, e, r);
  e = fma(-x, r, 1.0);
  r = fma(r, e, r);
  return r;
}

// ---------------- fp64 digamma/trigamma via shift-8 + asymptotic ----------------

__device__ __forceinline__ void digtri8(double x, double& dg, double& tg) {
  double i0 = frcp(x),       i1 = frcp(x + 1.0);
  double i2 = frcp(x + 2.0), i3 = frcp(x + 3.0);
  double i4 = frcp(x + 4.0), i5 = frcp(x + 5.0);
  double i6 = frcp(x + 6.0), i7 = frcp(x + 7.0);
  double rd = (i0 + i1) + (i2 + i3) + ((i4 + i5) + (i6 + i7));
  double rt = (i0 * i0 + i1 * i1) + (i2 * i2 + i3 * i3) +
              ((i4 * i4 + i5 * i5) + (i6 * i6 + i7 * i7));
  double y = x + 8.0;
  double yi = frcp(y), f = yi * yi;
  dg = log(y) - 0.5 * yi
     - f * (1.0 / 12 - f * (1.0 / 120 - f * (1.0 / 252 - f * (1.0 / 240 - f * (1.0 / 132)))))
     - rd;
  tg = rt + yi + 0.5 * f
     + f * yi * (1.0 / 6 - f * (1.0 / 30 - f * (1.0 / 42 - f * (1.0 / 30))));
}

__device__ __forceinline__ double wsum16(double v) {
#pragma unroll
  for (int off = 1; off < 16; off <<= 1) v += __shfl_xor(v, off);
  return v;
}

// ---------------- Kernel 2: coalesced reduce + fast-rcp Newton (fp64) -----------
// (byte-identical to previous round — control variable)

__global__ __launch_bounds__(1024) void dir_newton_kernel(
    const float* __restrict__ partials, float* __restrict__ out,
    int nparts, double nrows) {
  __shared__ double tot[NSTATS];
  const int tid = threadIdx.x;

  {
    const int j = tid >> 5;        // series (30 active of 32)
    const int k = tid & 31;
    double s = 0.0;
    if (j < NSTATS) {
      const float* __restrict__ base = partials + (size_t)j * nparts;
      const int nv4 = nparts >> 2;
      const f4* __restrict__ b4 = (const f4*)base;
      // coalesced: 32 lanes x 16B = 512B contiguous per instruction
      for (int b = k; b < nv4; b += 32) {
        f4 v = b4[b];
        s += ((double)v.x + (double)v.y) + ((double)v.z + (double)v.w);
      }
      for (int b = (nv4 << 2) + k; b < nparts; b += 32)  // tail (nparts%4!=0 only)
        s += (double)base[b];
    }
#pragma unroll
    for (int off = 16; off >= 1; off >>= 1) s += __shfl_xor(s, off);
    if (j < NSTATS && k == 0) tot[j] = s;
  }
  __syncthreads();

  if (tid < 16) {
    const int c = tid;
    const bool act = (c < C);
    const double n = nrows;
    const double ninv = frcp(n);
    double m1 = 0.0, m2 = 0.0, lpa = 0.0;
    if (act) {
      m1 = tot[c] * ninv;
      m2 = tot[C + c] * ninv;
      lpa = tot[2 * C + c] * ninv;
    }
    double ratio = act ? (m1 - m2) * frcp(m2 - m1 * m1) : 0.0;
    double rmean = wsum16(ratio) * (1.0 / (double)C);
    double a = act ? m1 * rmean : 0.0;

    double diff = 1e30;
    for (int k = 0; k < 100 && diff >= 1e-3; k++) {
      double S = wsum16(a);             // lanes 10..15 hold 0
      double dgl, tgl;                  // lanes 0..9: digtri(a); lane 10+: digtri(S)
      digtri8(act ? a : S, dgl, tgl);
      double dgS = __shfl(dgl, 10);
      double tgS = __shfl(tgl, 10);
      double g = act ? (dgS - dgl + lpa) * n : 0.0;
      double qinv = act ? -frcp(n * tgl) : 0.0;
      double z = n * tgS;
      double num = wsum16(g * qinv);
      double sq = wsum16(qinv);
      // b = num / (1/z + sq) = num * z / (1 + z*sq)   (one reciprocal)
      double b = num * z * frcp(fma(z, sq, 1.0));
      double anew = act ? a - (g - b) * qinv : 0.0;
      diff = wsum16(fabs(anew - a));
      a = anew;
    }
    if (act) out[c] = (float)a;
  }
}

// ---------------- launch ----------------

extern "C" void kernel_launch(void* const* d_in, const int* in_sizes, int n_in,
                              void* d_out, int out_size, void* d_ws, size_t ws_size,
                              hipStream_t stream) {
  const float* x = (const float*)d_in[0];
  const int total = in_sizes[0];
  const int nrows = total / C;

  int grid = NBLOCKS;
  size_t need = (size_t)NSTATS * grid * sizeof(float);
  if (need > ws_size) {
    grid = (int)(ws_size / (NSTATS * sizeof(float)));
    if (grid < 1) grid = 1;
  }

  float* partials = (float*)d_ws;
  dir_stats_kernel<<<grid, BLOCK, 0, stream>>>(x, partials, nrows, grid);
  // stats ran 2 passes -> sums doubled; pass 2n so the solve is bit-identical
  dir_newton_kernel<<<1, 1024, 0, stream>>>(partials, (float*)d_out, grid,
                                            2.0 * (double)nrows);
}

// Round 6
// 117.646 us; speedup vs baseline: 1.0872x; 1.0872x over previous
//
#include <hip/hip_runtime.h>
#include <math.h>

#define C 10
#define BLOCK 256
#define NBLOCKS 1024
#define WROWS 128                    // rows per wave-tile (2 rows per lane)
#define NSTATS (3 * C)               // 30 series

// 4B-aligned vector types: row base addresses are 40B multiples, so only
// dword alignment is guaranteed. gfx9+ global_load_dwordx4 needs only 4B.
typedef float f4 __attribute__((ext_vector_type(4), aligned(4)));
typedef float f2 __attribute__((ext_vector_type(2), aligned(4)));

// ---------------- row accumulate (softmax sufficient statistics) ----------------

__device__ __forceinline__ void accum10(f4 r0, f4 r1, f2 r2,
                                        float* __restrict__ s1,
                                        float* __restrict__ s2,
                                        float* __restrict__ sl) {
  float v[C];
  v[0] = r0.x; v[1] = r0.y; v[2] = r0.z; v[3] = r0.w;
  v[4] = r1.x; v[5] = r1.y; v[6] = r1.z; v[7] = r1.w;
  v[8] = r2.x; v[9] = r2.y;
  float mx = v[0];
#pragma unroll
  for (int c = 1; c < C; c++) mx = fmaxf(mx, v[c]);
  float e[C], se = 0.f;
#pragma unroll
  for (int c = 0; c < C; c++) { v[c] -= mx; e[c] = __expf(v[c]); se += e[c]; }
  float inv = 1.0f / se;
  float lse = __logf(se);
#pragma unroll
  for (int c = 0; c < C; c++) {
    float p = e[c] * inv;
    s1[c] += p;
    s2[c] = fmaf(p, p, s2[c]);
    sl[c] += v[c] - lse;             // log p = (x - mx) - lse
  }
}

// ---------------- Kernel 1: LDS-free stats (single pass — R4 version) -----------

__global__ __launch_bounds__(BLOCK) void dir_stats_kernel(
    const float* __restrict__ x, float* __restrict__ partials,
    int nrows, int nblocks) {
  __shared__ float red[4][NSTATS];
  const int tid = threadIdx.x;
  const int lane = tid & 63;
  const int wave = tid >> 6;

  const int gwave = blockIdx.x * 4 + wave;   // global wave id
  const int wstride = nblocks * 4;
  const int ntiles = nrows / WROWS;
  const int tailStart = ntiles * WROWS;

  float s1[C], s2[C], sl[C];
#pragma unroll
  for (int c = 0; c < C; c++) { s1[c] = 0.f; s2[c] = 0.f; sl[c] = 0.f; }

  int g = gwave;
  f4 a0 = 0, a1 = 0, b0 = 0, b1 = 0, n0 = 0, n1 = 0, m0 = 0, m1 = 0;
  f2 a2 = 0, b2 = 0, n2 = 0, m2 = 0;
  if (g < ntiles) {                          // prologue: rows (g*128+lane), (+64)
    const float* p = x + ((size_t)g * WROWS + lane) * C;
    a0 = *(const f4*)(p);       a1 = *(const f4*)(p + 4);   a2 = *(const f2*)(p + 8);
    b0 = *(const f4*)(p + 640); b1 = *(const f4*)(p + 644); b2 = *(const f2*)(p + 648);
  }
  while (g < ntiles) {
    const int gn = g + wstride;              // issue next tile's loads NOW
    if (gn < ntiles) {
      const float* p = x + ((size_t)gn * WROWS + lane) * C;
      n0 = *(const f4*)(p);       n1 = *(const f4*)(p + 4);   n2 = *(const f2*)(p + 8);
      m0 = *(const f4*)(p + 640); m1 = *(const f4*)(p + 644); m2 = *(const f2*)(p + 648);
    }
    accum10(a0, a1, a2, s1, s2, sl);         // compute on current regs (no dep on loads)
    accum10(b0, b1, b2, s1, s2, sl);
    a0 = n0; a1 = n1; a2 = n2;               // vmcnt wait lands here, after compute
    b0 = m0; b1 = m1; b2 = m2;
    g = gn;
  }

  if (gwave == wstride - 1) {                // tail rows (none when nrows%128==0)
    for (int rr = tailStart + lane; rr < nrows; rr += 64) {
      const float* r = x + (size_t)rr * C;
      f4 t0 = *(const f4*)(r);
      f4 t1 = *(const f4*)(r + 4);
      f2 t2 = *(const f2*)(r + 8);
      accum10(t0, t1, t2, s1, s2, sl);
    }
  }

  // block reduction: wave shuffle, then cross-wave via LDS (single barrier)
#pragma unroll
  for (int c = 0; c < C; c++) {
    float v1 = s1[c], v2 = s2[c], v3 = sl[c];
#pragma unroll
    for (int off = 32; off >= 1; off >>= 1) {
      v1 += __shfl_down(v1, off);
      v2 += __shfl_down(v2, off);
      v3 += __shfl_down(v3, off);
    }
    if (lane == 0) {
      red[wave][c] = v1;
      red[wave][C + c] = v2;
      red[wave][2 * C + c] = v3;
    }
  }
  __syncthreads();
  if (tid < NSTATS) {
    float tot = red[0][tid] + red[1][tid] + red[2][tid] + red[3][tid];
    partials[(size_t)tid * nblocks + blockIdx.x] = tot;   // SoA over blocks
  }
}

// ---------------- low-latency fp64 helpers (Newton solver) ----------------------

// fast fp64 reciprocal: v_rcp_f64 + 2 NR steps (<=1 ulp); divisors all positive.
__device__ __forceinline__ double frcp(double x) {
  double r;
  asm("v_rcp_f64 %0, %1" : "=v"(r) : "v"(x));
  double e = fma(-x, r, 1.0);
  r = fma(r, e, r);
  e = fma(-x, r, 1.0);
  r = fma(r, e, r);
  return r;
}

// DPP row-rotate on a double: pure-VALU cross-lane (~12cyc) vs ds_swizzle (~50cyc).
// row_ror:k rotates within each 16-lane row; sources must be active lanes.
template <int CTRL>
__device__ __forceinline__ double dpp_rot(double v) {
  long long l = __double_as_longlong(v);
  int lo = (int)(unsigned)(l & 0xFFFFFFFFu);
  int hi = (int)(unsigned)((unsigned long long)l >> 32);
  lo = __builtin_amdgcn_update_dpp(0, lo, CTRL, 0xF, 0xF, true);
  hi = __builtin_amdgcn_update_dpp(0, hi, CTRL, 0xF, 0xF, true);
  return __longlong_as_double(((long long)(unsigned)lo) |
                              ((long long)(unsigned)hi << 32));
}

// all-reduce sum over the 16-lane row via ror 1/2/4/8 (all lanes end with total,
// up to lane-dependent ulp-level association differences — benign here).
__device__ __forceinline__ double wsum16d(double v) {
  v += dpp_rot<0x121>(v);   // row_ror:1
  v += dpp_rot<0x122>(v);   // row_ror:2
  v += dpp_rot<0x124>(v);   // row_ror:4
  v += dpp_rot<0x128>(v);   // row_ror:8
  return v;
}

// broadcast lane 10's double to all lanes via v_readlane (SGPR, ~10cyc, uniform)
__device__ __forceinline__ double bcast10(double v) {
  long long l = __double_as_longlong(v);
  int lo = __builtin_amdgcn_readlane((int)(unsigned)(l & 0xFFFFFFFFu), 10);
  int hi = __builtin_amdgcn_readlane((int)(unsigned)((unsigned long long)l >> 32), 10);
  return __longlong_as_double(((long long)(unsigned)lo) |
                              ((long long)(unsigned)hi << 32));
}

__device__ __forceinline__ double uni(double v) {   // wave-uniform copy (lane 0)
  long long l = __double_as_longlong(v);
  int lo = __builtin_amdgcn_readfirstlane((int)(unsigned)(l & 0xFFFFFFFFu));
  int hi = __builtin_amdgcn_readfirstlane((int)(unsigned)((unsigned long long)l >> 32));
  return __longlong_as_double(((long long)(unsigned)lo) |
                              ((long long)(unsigned)hi << 32));
}

// custom fp64 log, x in [8, ~4000]: exponent extract + 2*atanh(f) Estrin series.
// ~1 ulp; replaces the library log's long serial software chain.
__device__ __forceinline__ double flog(double x) {
  long long b = __double_as_longlong(x);
  int e = (int)((b >> 52) & 0x7FF) - 1023;
  double m = __longlong_as_double((b & 0x000FFFFFFFFFFFFFLL) | 0x3FF0000000000000LL);
  int big = m > 1.4142135623730951;
  m = big ? 0.5 * m : m;                     // m in [0.7071, 1.4142]
  e += big;
  double f = (m - 1.0) * frcp(m + 1.0);      // |f| <= 0.1716
  double f2 = f * f;                         // <= 0.02944
  double f4_ = f2 * f2, f8_ = f4_ * f4_;
  // p = sum_{i=0..10} f2^i/(2i+1)   (trunc err < 1e-18 rel)
  double p01 = fma(f2, 1.0 / 3,  1.0);
  double p23 = fma(f2, 1.0 / 7,  1.0 / 5);
  double p45 = fma(f2, 1.0 / 11, 1.0 / 9);
  double p67 = fma(f2, 1.0 / 15, 1.0 / 13);
  double p89 = fma(f2, 1.0 / 19, 1.0 / 17);
  double q0 = fma(f4_, p23, p01);
  double q1 = fma(f4_, p67, p45);
  double q2 = fma(f4_, 1.0 / 21, p89);
  double r0 = fma(f8_, q1, q0);
  double p  = fma(f8_ * f8_, q2, r0);
  return fma((double)e, 0.6931471805599453, 2.0 * f * p);
}

// fp64 digamma/trigamma via shift-8 + asymptotic (flog on the critical path)
__device__ __forceinline__ void digtri8(double x, double& dg, double& tg) {
  double i0 = frcp(x),       i1 = frcp(x + 1.0);
  double i2 = frcp(x + 2.0), i3 = frcp(x + 3.0);
  double i4 = frcp(x + 4.0), i5 = frcp(x + 5.0);
  double i6 = frcp(x + 6.0), i7 = frcp(x + 7.0);
  double rd = (i0 + i1) + (i2 + i3) + ((i4 + i5) + (i6 + i7));
  double rt = (i0 * i0 + i1 * i1) + (i2 * i2 + i3 * i3) +
              ((i4 * i4 + i5 * i5) + (i6 * i6 + i7 * i7));
  double y = x + 8.0;
  double yi = frcp(y), f = yi * yi;
  dg = flog(y) - 0.5 * yi
     - f * (1.0 / 12 - f * (1.0 / 120 - f * (1.0 / 252 - f * (1.0 / 240 - f * (1.0 / 132)))))
     - rd;
  tg = rt + yi + 0.5 * f
     + f * yi * (1.0 / 6 - f * (1.0 / 30 - f * (1.0 / 42 - f * (1.0 / 30))));
}

// ---------------- Kernel 2: coalesced reduce + low-latency Newton (fp64) --------

__global__ __launch_bounds__(1024) void dir_newton_kernel(
    const float* __restrict__ partials, float* __restrict__ out,
    int nparts, double nrows) {
  __shared__ double tot[NSTATS];
  const int tid = threadIdx.x;

  {
    const int j = tid >> 5;        // series (30 active of 32)
    const int k = tid & 31;
    double s = 0.0;
    if (j < NSTATS) {
      const float* __restrict__ base = partials + (size_t)j * nparts;
      const int nv4 = nparts >> 2;
      const f4* __restrict__ b4 = (const f4*)base;
      // coalesced: 32 lanes x 16B = 512B contiguous per instruction
      for (int b = k; b < nv4; b += 32) {
        f4 v = b4[b];
        s += ((double)v.x + (double)v.y) + ((double)v.z + (double)v.w);
      }
      for (int b = (nv4 << 2) + k; b < nparts; b += 32)  // tail (nparts%4!=0 only)
        s += (double)base[b];
    }
#pragma unroll
    for (int off = 16; off >= 1; off >>= 1) s += __shfl_xor(s, off);
    if (j < NSTATS && k == 0) tot[j] = s;
  }
  __syncthreads();

  if (tid < 16) {                  // lanes 0..15 of wave 0 — all DPP sources active
    const int c = tid;
    const bool act = (c < C);
    const double n = nrows;
    const double ninv = frcp(n);
    double m1 = 0.0, m2 = 0.0, lpa = 0.0;
    if (act) {
      m1 = tot[c] * ninv;
      m2 = tot[C + c] * ninv;
      lpa = tot[2 * C + c] * ninv;
    }
    double ratio = act ? (m1 - m2) * frcp(m2 - m1 * m1) : 0.0;
    double rmean = wsum16d(ratio) * (1.0 / (double)C);
    double a = act ? m1 * rmean : 0.0;

    double S = wsum16d(a);                   // tracked incrementally below
    double diff = 1e30;
    for (int k = 0; k < 100 && diff >= 1e-3; k++) {
      double dgl, tgl;                       // lanes 0..9: digtri(a); 10..15: digtri(S)
      digtri8(act ? a : S, dgl, tgl);
      double dgS = bcast10(dgl);
      double tgS = bcast10(tgl);
      double g = act ? (dgS - dgl + lpa) * n : 0.0;
      double qinv = act ? -frcp(n * tgl) : 0.0;
      double z = n * tgS;
      double num = wsum16d(g * qinv);        // two independent DPP chains overlap
      double sq  = wsum16d(qinv);
      // b = num / (1/z + sq) = num * z / (1 + z*sq)   (one reciprocal)
      double b = num * z * frcp(fma(z, sq, 1.0));
      double step = act ? (g - b) * qinv : 0.0;
      a -= step;
      S -= wsum16d(step);                    // overlaps with the diff reduction
      diff = uni(wsum16d(fabs(step)));       // uniform -> no lane-divergent exit
    }
    if (act) out[c] = (float)a;
  }
}

// ---------------- launch ----------------

extern "C" void kernel_launch(void* const* d_in, const int* in_sizes, int n_in,
                              void* d_out, int out_size, void* d_ws, size_t ws_size,
                              hipStream_t stream) {
  const float* x = (const float*)d_in[0];
  const int total = in_sizes[0];
  const int nrows = total / C;

  int grid = NBLOCKS;
  size_t need = (size_t)NSTATS * grid * sizeof(float);
  if (need > ws_size) {
    grid = (int)(ws_size / (NSTATS * sizeof(float)));
    if (grid < 1) grid = 1;
  }

  float* partials = (float*)d_ws;
  dir_stats_kernel<<<grid, BLOCK, 0, stream>>>(x, partials, nrows, grid);
  dir_newton_kernel<<<1, 1024, 0, stream>>>(partials, (float*)d_out, grid, (double)nrows);
}